// Round 19
// baseline (663.398 us; speedup 1.0000x reference)
//
#include <hip/hip_runtime.h>
#include <hip/hip_bf16.h>
#include <stdint.h>

#define LSEQ   16384
#define NBATCH 8
#define MROWS  (NBATCH*LSEQ)   // 131072
#define CDIM   256
#define NHEADS 8
#define HDIM   32
#define NWIN   64
#define NSH    32
#define NHID   1024

typedef unsigned short u16;
typedef __attribute__((ext_vector_type(4))) float f32x4;
typedef __attribute__((ext_vector_type(8))) short s16x8;

__device__ __forceinline__ u16 f2bf(float f) {
  union { float f; unsigned u; } c; c.f = f;
  unsigned r = c.u + 0x7FFFu + ((c.u >> 16) & 1u);
  return (u16)(r >> 16);
}

// fast GELU: x*sigmoid(1.5957691*(x+0.044715x^3)) == tanh-approx GELU
__device__ __forceinline__ float gelu_fast(float v) {
  float t = v * v;
  float u2 = v * fmaf(t, 0.0713548162726f, 1.59576912161f);
  float e = __expf(u2);
  float r = __builtin_amdgcn_rcpf(e + 1.f);
  return fmaf(-v, r, v); // v*e/(e+1)
}

// ---------------- weight transpose fp32->bf16: out[n][k] = in[k][n] ----------------
__global__ __launch_bounds__(256) void wtrans_kernel(const float* __restrict__ in,
                                                     u16* __restrict__ out, int K, int N) {
  __shared__ float tile[64][65];
  int k0 = blockIdx.x * 64, n0 = blockIdx.y * 64;
  int t = threadIdx.x;
  int r = t >> 4, cb = (t & 15) * 4;
#pragma unroll
  for (int p = 0; p < 4; ++p) {
    const float4 v = *(const float4*)(in + (size_t)(k0 + r + p*16) * N + n0 + cb);
    tile[r+p*16][cb+0] = v.x; tile[r+p*16][cb+1] = v.y;
    tile[r+p*16][cb+2] = v.z; tile[r+p*16][cb+3] = v.w;
  }
  __syncthreads();
#pragma unroll
  for (int p = 0; p < 4; ++p) {
    int nl = r + p*16;
    ushort4 o;
    o.x = f2bf(tile[cb+0][nl]); o.y = f2bf(tile[cb+1][nl]);
    o.z = f2bf(tile[cb+2][nl]); o.w = f2bf(tile[cb+3][nl]);
    *(ushort4*)(out + (size_t)(n0+nl)*K + k0 + cb) = o;
  }
}

// ---------------- LN1 + shift(-32, zero tail) -> bf16 ----------------
__global__ __launch_bounds__(256) void ln_shift_kernel(const float* __restrict__ x,
                                                       const float* __restrict__ g,
                                                       const float* __restrict__ b,
                                                       u16* __restrict__ out) {
  int row  = blockIdx.x * 4 + (threadIdx.x >> 6);
  int lane = threadIdx.x & 63;
  u16* op = out + (size_t)row * CDIM + lane*4;
  int l  = row & (LSEQ-1);
  int ls = l + NSH;
  if (ls >= LSEQ) { *(ushort4*)op = make_ushort4(0,0,0,0); return; }
  const float4 v = *(const float4*)(x + ((size_t)(row - l) + ls) * CDIM + lane*4);
  float s  = v.x+v.y+v.z+v.w;
  float s2 = v.x*v.x + v.y*v.y + v.z*v.z + v.w*v.w;
#pragma unroll
  for (int m = 1; m < 64; m <<= 1) { s += __shfl_xor(s, m); s2 += __shfl_xor(s2, m); }
  float mean = s * (1.f/CDIM);
  float rs = rsqrtf(s2*(1.f/CDIM) - mean*mean + 1e-5f);
  const float4 gv = *(const float4*)(g + lane*4);
  const float4 bv = *(const float4*)(b + lane*4);
  ushort4 o;
  o.x = f2bf((v.x-mean)*rs*gv.x + bv.x);
  o.y = f2bf((v.y-mean)*rs*gv.y + bv.y);
  o.z = f2bf((v.z-mean)*rs*gv.z + bv.z);
  o.w = f2bf((v.w-mean)*rs*gv.w + bv.w);
  *(ushort4*)op = o;
}

// ---------------- GEMM (QKV): C[M,768] = A[M,256] * BT[768,256]^T, 128x128x64 tiles ----------------
template<int KDIM, int NDIM>
__global__ __launch_bounds__(256) void gemm_kernel(const u16* __restrict__ A,
                                                   const u16* __restrict__ BT,
                                                   const float* __restrict__ bias,
                                                   u16* __restrict__ Cout) {
  __shared__ __align__(16) u16 As[128*64];
  __shared__ __align__(16) u16 Bs[128*64];
  const int t = threadIdx.x, wave = t >> 6, lane = t & 63;
  constexpr int NT_N = NDIM / 128;
  constexpr int G = 32;
  const int bid = blockIdx.x;
  const int chunk = bid / (G * NT_N);
  const int rem = bid - chunk * (G * NT_N);
  const int tn = rem / G;
  const int tm = chunk * G + (rem - tn * G);
  f32x4 acc[4][4];
#pragma unroll
  for (int m = 0; m < 4; ++m)
#pragma unroll
    for (int n = 0; n < 4; ++n) acc[m][n] = (f32x4){0.f,0.f,0.f,0.f};

  const size_t Aoff = (size_t)tm * 128 * KDIM;
  const size_t Boff = (size_t)tn * 128 * KDIM;
  int rowS[4], kblkS[4];
#pragma unroll
  for (int p = 0; p < 4; ++p) {
    int i = p*256 + t; rowS[p] = i >> 3;
    kblkS[p] = ((i & 7) ^ (rowS[p] & 7)) * 8;
  }
  const int wr = (wave >> 1) * 64, wc = (wave & 1) * 64;

  for (int kt = 0; kt < KDIM/64; ++kt) {
    const int k0 = kt * 64;
#pragma unroll
    for (int p = 0; p < 4; ++p) {
      __builtin_amdgcn_global_load_lds(
        (const __attribute__((address_space(1))) void*)(A + Aoff + (size_t)rowS[p]*KDIM + k0 + kblkS[p]),
        (__attribute__((address_space(3))) void*)(As + (p*256 + wave*64)*8), 16, 0, 0);
      __builtin_amdgcn_global_load_lds(
        (const __attribute__((address_space(1))) void*)(BT + Boff + (size_t)rowS[p]*KDIM + k0 + kblkS[p]),
        (__attribute__((address_space(3))) void*)(Bs + (p*256 + wave*64)*8), 16, 0, 0);
    }
    asm volatile("s_waitcnt vmcnt(0)" ::: "memory");
    __syncthreads();
#pragma unroll
    for (int kk = 0; kk < 2; ++kk) {
      s16x8 af[4], bf[4];
#pragma unroll
      for (int m = 0; m < 4; ++m) {
        int r = wr + m*16 + (lane & 15);
        int slot = (kk*4 + (lane >> 4)) ^ (r & 7);
        af[m] = *(const s16x8*)&As[r*64 + slot*8];
      }
#pragma unroll
      for (int n = 0; n < 4; ++n) {
        int r = wc + n*16 + (lane & 15);
        int slot = (kk*4 + (lane >> 4)) ^ (r & 7);
        bf[n] = *(const s16x8*)&Bs[r*64 + slot*8];
      }
#pragma unroll
      for (int m = 0; m < 4; ++m)
#pragma unroll
        for (int n = 0; n < 4; ++n)
          acc[m][n] = __builtin_amdgcn_mfma_f32_16x16x32_bf16(bf[n], af[m], acc[m][n], 0, 0, 0);
    }
    __syncthreads();
  }

  const int g = lane >> 4, c0 = lane & 15;
  const size_t row0 = (size_t)tm*128 + wr;
  const int col0 = tn*128 + wc;
  float4 bvv[4];
#pragma unroll
  for (int n = 0; n < 4; ++n) bvv[n] = *(const float4*)(bias + col0 + n*16 + g*4);
#pragma unroll
  for (int m = 0; m < 4; ++m) {
    size_t R = row0 + m*16 + c0;
    u16* orow = Cout + R * NDIM + col0 + g*4;
#pragma unroll
    for (int n = 0; n < 4; ++n) {
      ushort4 o;
      o.x = f2bf(acc[m][n][0] + bvv[n].x);
      o.y = f2bf(acc[m][n][1] + bvv[n].y);
      o.z = f2bf(acc[m][n][2] + bvv[n].z);
      o.w = f2bf(acc[m][n][3] + bvv[n].w);
      *(ushort4*)(orow + n*16) = o;
    }
  }
}

// ---------------- fused proj + residual + LN2, destination-indexed ----------------
__global__ __launch_bounds__(256) void proj_ln_kernel(const u16* __restrict__ A,
                                                      const u16* __restrict__ BT,
                                                      const float* __restrict__ bias,
                                                      const float* __restrict__ x,
                                                      const float* __restrict__ g2,
                                                      const float* __restrict__ b2,
                                                      float* __restrict__ out,
                                                      u16* __restrict__ ln_out) {
  __shared__ __align__(16) u16 As[64*64];    // 8 KB
  __shared__ __align__(16) u16 Bs[256*64];   // 32 KB
  const int t = threadIdx.x, wave = t >> 6, lane = t & 63;
  const int g = lane >> 4, c0 = lane & 15;
  const int row0 = blockIdx.x * 64;

  f32x4 acc[16];
#pragma unroll
  for (int n = 0; n < 16; ++n) acc[n] = (f32x4){0.f,0.f,0.f,0.f};

  for (int kt = 0; kt < 4; ++kt) {
    const int k0 = kt * 64;
#pragma unroll
    for (int p = 0; p < 2; ++p) {
      int i = p*256 + t;
      int r = i >> 3;
      int srow = row0 - NSH + r; if (srow < 0) srow = 0;
      int kb = ((i & 7) ^ (r & 7)) * 8;
      __builtin_amdgcn_global_load_lds(
        (const __attribute__((address_space(1))) void*)(A + (size_t)srow*CDIM + k0 + kb),
        (__attribute__((address_space(3))) void*)(As + i*8), 16, 0, 0);
    }
#pragma unroll
    for (int p = 0; p < 8; ++p) {
      int i = p*256 + t;
      int r = i >> 3;
      int kb = ((i & 7) ^ (r & 7)) * 8;
      __builtin_amdgcn_global_load_lds(
        (const __attribute__((address_space(1))) void*)(BT + (size_t)r*CDIM + k0 + kb),
        (__attribute__((address_space(3))) void*)(Bs + i*8), 16, 0, 0);
    }
    asm volatile("s_waitcnt vmcnt(0)" ::: "memory");
    __syncthreads();
#pragma unroll
    for (int kk = 0; kk < 2; ++kk) {
      const int ar = wave*16 + c0;
      s16x8 af = *(const s16x8*)&As[ar*64 + (((kk*4 + g) ^ (ar & 7)) * 8)];
#pragma unroll
      for (int nn = 0; nn < 4; ++nn) {
        s16x8 bf[4];
#pragma unroll
        for (int q = 0; q < 4; ++q) {
          int rn = (nn*4 + q)*16 + c0;
          bf[q] = *(const s16x8*)&Bs[rn*64 + (((kk*4 + g) ^ (rn & 7)) * 8)];
        }
#pragma unroll
        for (int q = 0; q < 4; ++q)
          acc[nn*4+q] = __builtin_amdgcn_mfma_f32_16x16x32_bf16(bf[q], af, acc[nn*4+q], 0, 0, 0);
      }
    }
    __syncthreads();
  }

  const int D = row0 + wave*16 + c0;
  const int l_d = D & (LSEQ-1);
  const bool addp = (l_d >= NSH);
  float s = 0.f, s2 = 0.f;
  f32x4 x1v[16];
#pragma unroll
  for (int n = 0; n < 16; ++n) {
    const int col = n*16 + g*4;
    const float4 xv = *(const float4*)(x + (size_t)D*CDIM + col);
    const float4 bv = *(const float4*)(bias + col);
    f32x4 v;
    v[0] = addp ? xv.x + acc[n][0] + bv.x : xv.x;
    v[1] = addp ? xv.y + acc[n][1] + bv.y : xv.y;
    v[2] = addp ? xv.z + acc[n][2] + bv.z : xv.z;
    v[3] = addp ? xv.w + acc[n][3] + bv.w : xv.w;
    *(f32x4*)(out + (size_t)D*CDIM + col) = v;
    x1v[n] = v;
    s  += v[0]+v[1]+v[2]+v[3];
    s2 += v[0]*v[0]+v[1]*v[1]+v[2]*v[2]+v[3]*v[3];
  }
  s  += __shfl_xor(s, 16);  s  += __shfl_xor(s, 32);
  s2 += __shfl_xor(s2, 16); s2 += __shfl_xor(s2, 32);
  const float mean = s * (1.f/CDIM);
  const float rs = rsqrtf(s2*(1.f/CDIM) - mean*mean + 1e-5f);
#pragma unroll
  for (int n = 0; n < 16; ++n) {
    const int col = n*16 + g*4;
    const float4 gv = *(const float4*)(g2 + col);
    const float4 bv = *(const float4*)(b2 + col);
    ushort4 o;
    o.x = f2bf((x1v[n][0]-mean)*rs*gv.x + bv.x);
    o.y = f2bf((x1v[n][1]-mean)*rs*gv.y + bv.y);
    o.z = f2bf((x1v[n][2]-mean)*rs*gv.z + bv.z);
    o.w = f2bf((x1v[n][3]-mean)*rs*gv.w + bv.w);
    *(ushort4*)(ln_out + (size_t)D*CDIM + col) = o;
  }
}

// ---------------- fused MLP v7: 32-row blocks, LDS 52KB -> 3 blocks/CU ----------------
// Same v4 schedule per hc2 (16 iters): W1'[64][256] stage -> drain -> FC1 (16 MFMA/wave)
// -> W2'[256][64] stage (hidden under GELU) -> FC2 (16 MFMA/wave).
// Block = 32 rows: Xs 16KB + Ws 32KB + Hs 4KB = 52KB -> 3 blocks/CU (was 2).
// Per-output accumulation order identical to v4 -> bit-identical results.
__global__ __launch_bounds__(256) void mlp_kernel(const u16* __restrict__ A,    // LN2 out [M][256] bf16
                                                  const u16* __restrict__ W1T,  // [1024][256] bf16
                                                  const u16* __restrict__ W2T,  // [256][1024] bf16
                                                  const float* __restrict__ b1,
                                                  const float* __restrict__ b2,
                                                  float* __restrict__ out) {    // x1 in, result out
  __shared__ __align__(16) u16 Xs[32*256];   // 16 KB
  __shared__ __align__(16) u16 Ws[64*256];   // 32 KB: W1' [64][256] or W2' [256][64]
  __shared__ __align__(16) u16 Hs[32*64];    // 4 KB
  const int t = threadIdx.x, wave = t >> 6, lane = t & 63;
  const int g = lane >> 4, c0 = lane & 15;
  const int row0 = blockIdx.x * 32;

  // stage Xs: [32][256] (4 loads/thread)
#pragma unroll
  for (int p = 0; p < 4; ++p) {
    int i = p*256 + t, r = i >> 5, cb = i & 31;
    __builtin_amdgcn_global_load_lds(
      (const __attribute__((address_space(1))) void*)(A + (size_t)(row0 + r)*CDIM + ((cb ^ (r & 7))*8)),
      (__attribute__((address_space(3))) void*)(Xs + i*8), 16, 0, 0);
  }
  f32x4 acc2[2][4];
#pragma unroll
  for (int m = 0; m < 2; ++m)
#pragma unroll
    for (int n = 0; n < 4; ++n) acc2[m][n] = (f32x4){0.f,0.f,0.f,0.f};

#pragma unroll 1
  for (int hc2 = 0; hc2 < 16; ++hc2) {
    const float4 bv1 = *(const float4*)(b1 + hc2*64 + wave*16 + g*4);
    // ---- stage W1' [64 hidden][256 k] (8 loads); Ws free per loop-end barrier ----
#pragma unroll
    for (int p = 0; p < 8; ++p) {
      int i = p*256 + t, r = i >> 5, cb = i & 31;
      __builtin_amdgcn_global_load_lds(
        (const __attribute__((address_space(1))) void*)(W1T + (size_t)(hc2*64 + r)*256 + ((cb ^ (r & 7))*8)),
        (__attribute__((address_space(3))) void*)(Ws + i*8), 16, 0, 0);
    }
    asm volatile("s_waitcnt vmcnt(0)" ::: "memory");
    __syncthreads();                       // W1' (+Xs first iter) ready
    // ---- FC1: 16 MFMAs/wave ----
    f32x4 acc1[2];
    acc1[0] = (f32x4){0.f,0.f,0.f,0.f};
    acc1[1] = (f32x4){0.f,0.f,0.f,0.f};
#pragma unroll
    for (int q = 0; q < 8; ++q) {          // k-chunk 0..7 over K=256
      s16x8 af[2];
#pragma unroll
      for (int m = 0; m < 2; ++m) {
        int r = m*16 + c0;
        af[m] = *(const s16x8*)&Xs[r*256 + (((q*4 + g) ^ (r & 7))*8)];
      }
      int rw = wave*16 + c0;
      s16x8 bf = *(const s16x8*)&Ws[rw*256 + (((q*4 + g) ^ (rw & 7))*8)];
#pragma unroll
      for (int m = 0; m < 2; ++m)
        acc1[m] = __builtin_amdgcn_mfma_f32_16x16x32_bf16(bf, af[m], acc1[m], 0, 0, 0);
    }
    __syncthreads();                       // all W1' reads done; Ws free
    // ---- issue W2' [256 out][64 k] (8 loads), hidden under GELU ----
#pragma unroll
    for (int p = 0; p < 8; ++p) {
      int i = p*256 + t, r = i >> 3, cb = i & 7;
      __builtin_amdgcn_global_load_lds(
        (const __attribute__((address_space(1))) void*)(W2T + (size_t)r*NHID + hc2*64 + ((cb ^ (r & 7))*8)),
        (__attribute__((address_space(3))) void*)(Ws + i*8), 16, 0, 0);
    }
    // ---- GELU -> Hs [32][64] swizzled (result col = wave*16 + g*4 + j) ----
    {
#pragma unroll
      for (int m = 0; m < 2; ++m) {
        int r = m*16 + c0;
        ushort4 o;
        o.x = f2bf(gelu_fast(acc1[m][0] + bv1.x));
        o.y = f2bf(gelu_fast(acc1[m][1] + bv1.y));
        o.z = f2bf(gelu_fast(acc1[m][2] + bv1.z));
        o.w = f2bf(gelu_fast(acc1[m][3] + bv1.w));
        int colb = wave*2 + (g >> 1);      // 16B chunk 0..7
        *(ushort4*)((char*)Hs + r*128 + ((colb ^ (r & 7)) << 4) + (g & 1)*8) = o;
      }
    }
    asm volatile("s_waitcnt vmcnt(0)" ::: "memory");
    __syncthreads();                       // W2' + Hs ready
    // ---- FC2: 16 MFMAs/wave (accumulate into acc2) ----
#pragma unroll
    for (int kk = 0; kk < 2; ++kk) {
      s16x8 af[2], bf[4];
#pragma unroll
      for (int m = 0; m < 2; ++m) {
        int r = m*16 + c0;
        af[m] = *(const s16x8*)&Hs[r*64 + (((kk*4 + g) ^ (r & 7))*8)];
      }
#pragma unroll
      for (int n = 0; n < 4; ++n) {
        int rw = wave*64 + n*16 + c0;
        bf[n] = *(const s16x8*)&Ws[rw*64 + (((kk*4 + g) ^ (rw & 7))*8)];
      }
#pragma unroll
      for (int m = 0; m < 2; ++m)
#pragma unroll
        for (int n = 0; n < 4; ++n)
          acc2[m][n] = __builtin_amdgcn_mfma_f32_16x16x32_bf16(bf[n], af[m], acc2[m][n], 0, 0, 0);
    }
    __syncthreads();                       // Ws + Hs reads done before next hc2
  }
  // ---- epilogue: out = x1 + acc2 + b2
  float4 b2v[4];
#pragma unroll
  for (int n = 0; n < 4; ++n) b2v[n] = *(const float4*)(b2 + wave*64 + n*16 + g*4);
#pragma unroll
  for (int m = 0; m < 2; ++m) {
    size_t base = (size_t)(row0 + m*16 + c0)*CDIM + wave*64 + g*4;
#pragma unroll
    for (int n = 0; n < 4; ++n) {
      float4 rv = *(const float4*)(out + base + n*16);
      float4 o;
      o.x = rv.x + acc2[m][n][0] + b2v[n].x;
      o.y = rv.y + acc2[m][n][1] + b2v[n].y;
      o.z = rv.z + acc2[m][n][2] + b2v[n].z;
      o.w = rv.w + acc2[m][n][3] + b2v[n].w;
      *(float4*)(out + base + n*16) = o;
    }
  }
}

// ---------------- windowed attention ----------------
__global__ __launch_bounds__(256) void attn_kernel(const u16* __restrict__ qkv,
                                                   const float* __restrict__ rpb,
                                                   u16* __restrict__ out) {
  __shared__ __align__(16) u16 VT[NHEADS*HDIM*NWIN];
  __shared__ __align__(16) u16 Pl[4*NWIN*NWIN];
  __shared__ float biasl[NHEADS][128];
  const int t = threadIdx.x, wave = t >> 6, lane = t & 63;
  const int g = lane >> 4, c0 = lane & 15;
  const size_t rowbase = (size_t)blockIdx.x * NWIN;

  for (int e = t; e < NHEADS*128; e += 256) {
    int h = e >> 7, i = e & 127;
    biasl[h][i] = (i < 2*NWIN-1) ? rpb[i*NHEADS + h] : 0.f;
  }
  {
    int cA = t >> 5;
    int inner = t & 31;
    int hh = inner >> 2, d0 = (inner & 3) * 8;
#pragma unroll
    for (int p = 0; p < 8; ++p) {
      int c = p*8 + cA;
      s16x8 v = *(const s16x8*)&qkv[(rowbase + c)*768 + 512 + hh*32 + d0];
#pragma unroll
      for (int j = 0; j < 8; ++j) {
        int d = d0 + j;
        int slot = (c >> 3) ^ (d & 7) ^ hh;
        *(u16*)((char*)VT + hh*4096 + d*128 + slot*16 + (c & 7)*2) = (u16)v[j];
      }
    }
  }
  __syncthreads();

  const float scale = 0.17677669529663687f;
#pragma unroll 1
  for (int rep = 0; rep < 2; ++rep) {
    const int h = wave*2 + rep;
    s16x8 qf[4], kf[4];
#pragma unroll
    for (int m = 0; m < 4; ++m)
      qf[m] = *(const s16x8*)&qkv[(rowbase + m*16 + c0)*768 + h*32 + g*8];
#pragma unroll
    for (int n = 0; n < 4; ++n)
      kf[n] = *(const s16x8*)&qkv[(rowbase + n*16 + c0)*768 + 256 + h*32 + g*8];
    f32x4 sa[4][4];
#pragma unroll
    for (int m = 0; m < 4; ++m)
#pragma unroll
      for (int n = 0; n < 4; ++n) sa[m][n] = (f32x4){0.f,0.f,0.f,0.f};
#pragma unroll
    for (int m = 0; m < 4; ++m)
#pragma unroll
      for (int n = 0; n < 4; ++n)
        sa[m][n] = __builtin_amdgcn_mfma_f32_16x16x32_bf16(qf[m], kf[n], sa[m][n], 0, 0, 0);
#pragma unroll
    for (int m = 0; m < 4; ++m)
#pragma unroll
      for (int n = 0; n < 4; ++n) {
        int idx0 = (m-n)*16 + 4*g - c0 + 63;
#pragma unroll
        for (int j = 0; j < 4; ++j)
          sa[m][n][j] = sa[m][n][j]*scale + biasl[h][idx0 + j];
      }
    float rm[4][4], rsum[4][4];
#pragma unroll
    for (int m = 0; m < 4; ++m)
#pragma unroll
      for (int j = 0; j < 4; ++j) {
        float mx = fmaxf(fmaxf(sa[m][0][j], sa[m][1][j]), fmaxf(sa[m][2][j], sa[m][3][j]));
        mx = fmaxf(mx, __shfl_xor(mx, 1));
        mx = fmaxf(mx, __shfl_xor(mx, 2));
        mx = fmaxf(mx, __shfl_xor(mx, 4));
        mx = fmaxf(mx, __shfl_xor(mx, 8));
        rm[m][j] = mx;
      }
#pragma unroll
    for (int m = 0; m < 4; ++m)
#pragma unroll
      for (int n = 0; n < 4; ++n)
#pragma unroll
        for (int j = 0; j < 4; ++j)
          sa[m][n][j] = __expf(sa[m][n][j] - rm[m][j]);
#pragma unroll
    for (int m = 0; m < 4; ++m)
#pragma unroll
      for (int j = 0; j < 4; ++j) {
        float s = sa[m][0][j] + sa[m][1][j] + sa[m][2][j] + sa[m][3][j];
        s += __shfl_xor(s, 1);
        s += __shfl_xor(s, 2);
        s += __shfl_xor(s, 4);
        s += __shfl_xor(s, 8);
        rsum[m][j] = 1.f / s;
      }
    asm volatile("s_waitcnt lgkmcnt(0)" ::: "memory");
#pragma unroll
    for (int m = 0; m < 4; ++m)
#pragma unroll
      for (int n = 0; n < 4; ++n)
#pragma unroll
        for (int j = 0; j < 4; ++j) {
          int r = m*16 + 4*g + j, c = n*16 + c0;
          *(u16*)((char*)Pl + wave*8192 + r*128 + (((c>>3)^(r&7))*16) + (c&7)*2)
            = f2bf(sa[m][n][j] * rsum[m][j]);
        }
    asm volatile("s_waitcnt lgkmcnt(0)" ::: "memory");
    __builtin_amdgcn_sched_barrier(0);
    f32x4 oa[4][2];
#pragma unroll
    for (int m = 0; m < 4; ++m) { oa[m][0] = (f32x4){0.f,0.f,0.f,0.f}; oa[m][1] = (f32x4){0.f,0.f,0.f,0.f}; }
#pragma unroll
    for (int kk = 0; kk < 2; ++kk) {
      s16x8 pa[4], vb[2];
#pragma unroll
      for (int m = 0; m < 4; ++m) {
        int r = m*16 + c0;
        int slot = (kk*4 + g) ^ (r & 7);
        pa[m] = *(const s16x8*)((const char*)Pl + wave*8192 + r*128 + slot*16);
      }
#pragma unroll
      for (int n = 0; n < 2; ++n) {
        int d = n*16 + c0;
        int slot = (kk*4 + g) ^ (d & 7) ^ h;
        vb[n] = *(const s16x8*)((const char*)VT + h*4096 + d*128 + slot*16);
      }
#pragma unroll
      for (int m = 0; m < 4; ++m)
#pragma unroll
        for (int n = 0; n < 2; ++n)
          oa[m][n] = __builtin_amdgcn_mfma_f32_16x16x32_bf16(vb[n], pa[m], oa[m][n], 0, 0, 0);
    }
#pragma unroll
    for (int m = 0; m < 4; ++m) {
      u16* op = out + (rowbase + m*16 + c0)*CDIM + h*32 + g*4;
#pragma unroll
      for (int n = 0; n < 2; ++n) {
        ushort4 o;
        o.x = f2bf(oa[m][n][0]); o.y = f2bf(oa[m][n][1]);
        o.z = f2bf(oa[m][n][2]); o.w = f2bf(oa[m][n][3]);
        *(ushort4*)(op + n*16) = o;
      }
    }
  }
}

extern "C" void kernel_launch(void* const* d_in, const int* in_sizes, int n_in,
                              void* d_out, int out_size, void* d_ws, size_t ws_size,
                              hipStream_t stream) {
  const float* x      = (const float*)d_in[0];
  const float* g1     = (const float*)d_in[1];
  const float* b1     = (const float*)d_in[2];
  const float* qkv_w  = (const float*)d_in[3];
  const float* qkv_b  = (const float*)d_in[4];
  const float* rpb    = (const float*)d_in[5];
  const float* proj_w = (const float*)d_in[6];
  const float* proj_b = (const float*)d_in[7];
  const float* g2     = (const float*)d_in[8];
  const float* b2     = (const float*)d_in[9];
  const float* fc1_w  = (const float*)d_in[10];
  const float* fc1_b  = (const float*)d_in[11];
  const float* fc2_w  = (const float*)d_in[12];
  const float* fc2_b  = (const float*)d_in[13];
  float* out = (float*)d_out;

  u16* R0     = (u16*)d_ws;
  u16* R1     = R0 + (size_t)MROWS*768;
  u16* qkvwT  = R1 + (size_t)MROWS*1024;
  u16* projwT = qkvwT + 768*256;
  u16* fc1wT  = projwT + 256*256;
  u16* fc2wT  = fc1wT + 1024*256;

  wtrans_kernel<<<dim3(4, 12), 256, 0, stream>>>(qkv_w, qkvwT, 256, 768);
  wtrans_kernel<<<dim3(4, 4),  256, 0, stream>>>(proj_w, projwT, 256, 256);
  wtrans_kernel<<<dim3(4, 16), 256, 0, stream>>>(fc1_w, fc1wT, 256, 1024);
  wtrans_kernel<<<dim3(16, 4), 256, 0, stream>>>(fc2_w, fc2wT, 1024, 256);

  constexpr int NT_M = MROWS/128;
  ln_shift_kernel<<<MROWS/4, 256, 0, stream>>>(x, g1, b1, R1);
  gemm_kernel<256, 768><<<NT_M*6, 256, 0, stream>>>(R1, qkvwT, qkv_b, R0);
  attn_kernel<<<MROWS/NWIN, 256, 0, stream>>>(R0, rpb, R1);
  proj_ln_kernel<<<MROWS/64, 256, 0, stream>>>(R1, projwT, proj_b, x, g2, b2, out, R0);
  mlp_kernel<<<MROWS/32, 256, 0, stream>>>(R0, fc1wT, fc2wT, fc1_b, fc2_b, out);
}

// Round 20
// 616.949 us; speedup vs baseline: 1.0753x; 1.0753x over previous
//
#include <hip/hip_runtime.h>
#include <hip/hip_bf16.h>
#include <stdint.h>

#define LSEQ   16384
#define NBATCH 8
#define MROWS  (NBATCH*LSEQ)   // 131072
#define CDIM   256
#define NHEADS 8
#define HDIM   32
#define NWIN   64
#define NSH    32
#define NHID   1024

typedef unsigned short u16;
typedef __attribute__((ext_vector_type(4))) float f32x4;
typedef __attribute__((ext_vector_type(8))) short s16x8;

__device__ __forceinline__ u16 f2bf(float f) {
  union { float f; unsigned u; } c; c.f = f;
  unsigned r = c.u + 0x7FFFu + ((c.u >> 16) & 1u);
  return (u16)(r >> 16);
}

// fast GELU: x*sigmoid(1.5957691*(x+0.044715x^3)) == tanh-approx GELU
__device__ __forceinline__ float gelu_fast(float v) {
  float t = v * v;
  float u2 = v * fmaf(t, 0.0713548162726f, 1.59576912161f);
  float e = __expf(u2);
  float r = __builtin_amdgcn_rcpf(e + 1.f);
  return fmaf(-v, r, v); // v*e/(e+1)
}

// ---------------- weight transpose fp32->bf16: out[n][k] = in[k][n] ----------------
__global__ __launch_bounds__(256) void wtrans_kernel(const float* __restrict__ in,
                                                     u16* __restrict__ out, int K, int N) {
  __shared__ float tile[64][65];
  int k0 = blockIdx.x * 64, n0 = blockIdx.y * 64;
  int t = threadIdx.x;
  int r = t >> 4, cb = (t & 15) * 4;
#pragma unroll
  for (int p = 0; p < 4; ++p) {
    const float4 v = *(const float4*)(in + (size_t)(k0 + r + p*16) * N + n0 + cb);
    tile[r+p*16][cb+0] = v.x; tile[r+p*16][cb+1] = v.y;
    tile[r+p*16][cb+2] = v.z; tile[r+p*16][cb+3] = v.w;
  }
  __syncthreads();
#pragma unroll
  for (int p = 0; p < 4; ++p) {
    int nl = r + p*16;
    ushort4 o;
    o.x = f2bf(tile[cb+0][nl]); o.y = f2bf(tile[cb+1][nl]);
    o.z = f2bf(tile[cb+2][nl]); o.w = f2bf(tile[cb+3][nl]);
    *(ushort4*)(out + (size_t)(n0+nl)*K + k0 + cb) = o;
  }
}

// ---------------- LN1 + shift(-32, zero tail) -> bf16 ----------------
__global__ __launch_bounds__(256) void ln_shift_kernel(const float* __restrict__ x,
                                                       const float* __restrict__ g,
                                                       const float* __restrict__ b,
                                                       u16* __restrict__ out) {
  int row  = blockIdx.x * 4 + (threadIdx.x >> 6);
  int lane = threadIdx.x & 63;
  u16* op = out + (size_t)row * CDIM + lane*4;
  int l  = row & (LSEQ-1);
  int ls = l + NSH;
  if (ls >= LSEQ) { *(ushort4*)op = make_ushort4(0,0,0,0); return; }
  const float4 v = *(const float4*)(x + ((size_t)(row - l) + ls) * CDIM + lane*4);
  float s  = v.x+v.y+v.z+v.w;
  float s2 = v.x*v.x + v.y*v.y + v.z*v.z + v.w*v.w;
#pragma unroll
  for (int m = 1; m < 64; m <<= 1) { s += __shfl_xor(s, m); s2 += __shfl_xor(s2, m); }
  float mean = s * (1.f/CDIM);
  float rs = rsqrtf(s2*(1.f/CDIM) - mean*mean + 1e-5f);
  const float4 gv = *(const float4*)(g + lane*4);
  const float4 bv = *(const float4*)(b + lane*4);
  ushort4 o;
  o.x = f2bf((v.x-mean)*rs*gv.x + bv.x);
  o.y = f2bf((v.y-mean)*rs*gv.y + bv.y);
  o.z = f2bf((v.z-mean)*rs*gv.z + bv.z);
  o.w = f2bf((v.w-mean)*rs*gv.w + bv.w);
  *(ushort4*)op = o;
}

// ---------------- GEMM (QKV): C[M,768] = A[M,256] * BT[768,256]^T, 128x128x64 tiles ----------------
template<int KDIM, int NDIM>
__global__ __launch_bounds__(256) void gemm_kernel(const u16* __restrict__ A,
                                                   const u16* __restrict__ BT,
                                                   const float* __restrict__ bias,
                                                   u16* __restrict__ Cout) {
  __shared__ __align__(16) u16 As[128*64];
  __shared__ __align__(16) u16 Bs[128*64];
  const int t = threadIdx.x, wave = t >> 6, lane = t & 63;
  constexpr int NT_N = NDIM / 128;
  constexpr int G = 32;
  const int bid = blockIdx.x;
  const int chunk = bid / (G * NT_N);
  const int rem = bid - chunk * (G * NT_N);
  const int tn = rem / G;
  const int tm = chunk * G + (rem - tn * G);
  f32x4 acc[4][4];
#pragma unroll
  for (int m = 0; m < 4; ++m)
#pragma unroll
    for (int n = 0; n < 4; ++n) acc[m][n] = (f32x4){0.f,0.f,0.f,0.f};

  const size_t Aoff = (size_t)tm * 128 * KDIM;
  const size_t Boff = (size_t)tn * 128 * KDIM;
  int rowS[4], kblkS[4];
#pragma unroll
  for (int p = 0; p < 4; ++p) {
    int i = p*256 + t; rowS[p] = i >> 3;
    kblkS[p] = ((i & 7) ^ (rowS[p] & 7)) * 8;
  }
  const int wr = (wave >> 1) * 64, wc = (wave & 1) * 64;

  for (int kt = 0; kt < KDIM/64; ++kt) {
    const int k0 = kt * 64;
#pragma unroll
    for (int p = 0; p < 4; ++p) {
      __builtin_amdgcn_global_load_lds(
        (const __attribute__((address_space(1))) void*)(A + Aoff + (size_t)rowS[p]*KDIM + k0 + kblkS[p]),
        (__attribute__((address_space(3))) void*)(As + (p*256 + wave*64)*8), 16, 0, 0);
      __builtin_amdgcn_global_load_lds(
        (const __attribute__((address_space(1))) void*)(BT + Boff + (size_t)rowS[p]*KDIM + k0 + kblkS[p]),
        (__attribute__((address_space(3))) void*)(Bs + (p*256 + wave*64)*8), 16, 0, 0);
    }
    asm volatile("s_waitcnt vmcnt(0)" ::: "memory");
    __syncthreads();
#pragma unroll
    for (int kk = 0; kk < 2; ++kk) {
      s16x8 af[4], bf[4];
#pragma unroll
      for (int m = 0; m < 4; ++m) {
        int r = wr + m*16 + (lane & 15);
        int slot = (kk*4 + (lane >> 4)) ^ (r & 7);
        af[m] = *(const s16x8*)&As[r*64 + slot*8];
      }
#pragma unroll
      for (int n = 0; n < 4; ++n) {
        int r = wc + n*16 + (lane & 15);
        int slot = (kk*4 + (lane >> 4)) ^ (r & 7);
        bf[n] = *(const s16x8*)&Bs[r*64 + slot*8];
      }
#pragma unroll
      for (int m = 0; m < 4; ++m)
#pragma unroll
        for (int n = 0; n < 4; ++n)
          acc[m][n] = __builtin_amdgcn_mfma_f32_16x16x32_bf16(bf[n], af[m], acc[m][n], 0, 0, 0);
    }
    __syncthreads();
  }

  const int g = lane >> 4, c0 = lane & 15;
  const size_t row0 = (size_t)tm*128 + wr;
  const int col0 = tn*128 + wc;
  float4 bvv[4];
#pragma unroll
  for (int n = 0; n < 4; ++n) bvv[n] = *(const float4*)(bias + col0 + n*16 + g*4);
#pragma unroll
  for (int m = 0; m < 4; ++m) {
    size_t R = row0 + m*16 + c0;
    u16* orow = Cout + R * NDIM + col0 + g*4;
#pragma unroll
    for (int n = 0; n < 4; ++n) {
      ushort4 o;
      o.x = f2bf(acc[m][n][0] + bvv[n].x);
      o.y = f2bf(acc[m][n][1] + bvv[n].y);
      o.z = f2bf(acc[m][n][2] + bvv[n].z);
      o.w = f2bf(acc[m][n][3] + bvv[n].w);
      *(ushort4*)(orow + n*16) = o;
    }
  }
}

// ---------------- fused proj + residual + LN2, destination-indexed ----------------
__global__ __launch_bounds__(256) void proj_ln_kernel(const u16* __restrict__ A,
                                                      const u16* __restrict__ BT,
                                                      const float* __restrict__ bias,
                                                      const float* __restrict__ x,
                                                      const float* __restrict__ g2,
                                                      const float* __restrict__ b2,
                                                      float* __restrict__ out,
                                                      u16* __restrict__ ln_out) {
  __shared__ __align__(16) u16 As[64*64];    // 8 KB
  __shared__ __align__(16) u16 Bs[256*64];   // 32 KB
  const int t = threadIdx.x, wave = t >> 6, lane = t & 63;
  const int g = lane >> 4, c0 = lane & 15;
  const int row0 = blockIdx.x * 64;

  f32x4 acc[16];
#pragma unroll
  for (int n = 0; n < 16; ++n) acc[n] = (f32x4){0.f,0.f,0.f,0.f};

  for (int kt = 0; kt < 4; ++kt) {
    const int k0 = kt * 64;
#pragma unroll
    for (int p = 0; p < 2; ++p) {
      int i = p*256 + t;
      int r = i >> 3;
      int srow = row0 - NSH + r; if (srow < 0) srow = 0;
      int kb = ((i & 7) ^ (r & 7)) * 8;
      __builtin_amdgcn_global_load_lds(
        (const __attribute__((address_space(1))) void*)(A + (size_t)srow*CDIM + k0 + kb),
        (__attribute__((address_space(3))) void*)(As + i*8), 16, 0, 0);
    }
#pragma unroll
    for (int p = 0; p < 8; ++p) {
      int i = p*256 + t;
      int r = i >> 3;
      int kb = ((i & 7) ^ (r & 7)) * 8;
      __builtin_amdgcn_global_load_lds(
        (const __attribute__((address_space(1))) void*)(BT + (size_t)r*CDIM + k0 + kb),
        (__attribute__((address_space(3))) void*)(Bs + i*8), 16, 0, 0);
    }
    asm volatile("s_waitcnt vmcnt(0)" ::: "memory");
    __syncthreads();
#pragma unroll
    for (int kk = 0; kk < 2; ++kk) {
      const int ar = wave*16 + c0;
      s16x8 af = *(const s16x8*)&As[ar*64 + (((kk*4 + g) ^ (ar & 7)) * 8)];
#pragma unroll
      for (int nn = 0; nn < 4; ++nn) {
        s16x8 bf[4];
#pragma unroll
        for (int q = 0; q < 4; ++q) {
          int rn = (nn*4 + q)*16 + c0;
          bf[q] = *(const s16x8*)&Bs[rn*64 + (((kk*4 + g) ^ (rn & 7)) * 8)];
        }
#pragma unroll
        for (int q = 0; q < 4; ++q)
          acc[nn*4+q] = __builtin_amdgcn_mfma_f32_16x16x32_bf16(bf[q], af, acc[nn*4+q], 0, 0, 0);
      }
    }
    __syncthreads();
  }

  const int D = row0 + wave*16 + c0;
  const int l_d = D & (LSEQ-1);
  const bool addp = (l_d >= NSH);
  float s = 0.f, s2 = 0.f;
  f32x4 x1v[16];
#pragma unroll
  for (int n = 0; n < 16; ++n) {
    const int col = n*16 + g*4;
    const float4 xv = *(const float4*)(x + (size_t)D*CDIM + col);
    const float4 bv = *(const float4*)(bias + col);
    f32x4 v;
    v[0] = addp ? xv.x + acc[n][0] + bv.x : xv.x;
    v[1] = addp ? xv.y + acc[n][1] + bv.y : xv.y;
    v[2] = addp ? xv.z + acc[n][2] + bv.z : xv.z;
    v[3] = addp ? xv.w + acc[n][3] + bv.w : xv.w;
    *(f32x4*)(out + (size_t)D*CDIM + col) = v;
    x1v[n] = v;
    s  += v[0]+v[1]+v[2]+v[3];
    s2 += v[0]*v[0]+v[1]*v[1]+v[2]*v[2]+v[3]*v[3];
  }
  s  += __shfl_xor(s, 16);  s  += __shfl_xor(s, 32);
  s2 += __shfl_xor(s2, 16); s2 += __shfl_xor(s2, 32);
  const float mean = s * (1.f/CDIM);
  const float rs = rsqrtf(s2*(1.f/CDIM) - mean*mean + 1e-5f);
#pragma unroll
  for (int n = 0; n < 16; ++n) {
    const int col = n*16 + g*4;
    const float4 gv = *(const float4*)(g2 + col);
    const float4 bv = *(const float4*)(b2 + col);
    ushort4 o;
    o.x = f2bf((x1v[n][0]-mean)*rs*gv.x + bv.x);
    o.y = f2bf((x1v[n][1]-mean)*rs*gv.y + bv.y);
    o.z = f2bf((x1v[n][2]-mean)*rs*gv.z + bv.z);
    o.w = f2bf((x1v[n][3]-mean)*rs*gv.w + bv.w);
    *(ushort4*)(ln_out + (size_t)D*CDIM + col) = o;
  }
}

// ---------------- fused MLP v4 (r14 verified best): 64-col hidden chunks ----------------
// Per hc2 (16 iters): stage W1'[64][256] (32KB) -> ONE drain -> 32 FC1 MFMAs
// -> issue W2'[256][64] (32KB) -> GELU (drain hides under VALU) -> 32 FC2 MFMAs.
__global__ __launch_bounds__(256) void mlp_kernel(const u16* __restrict__ A,    // LN2 out [M][256] bf16
                                                  const u16* __restrict__ W1T,  // [1024][256] bf16
                                                  const u16* __restrict__ W2T,  // [256][1024] bf16
                                                  const float* __restrict__ b1,
                                                  const float* __restrict__ b2,
                                                  float* __restrict__ out) {    // x1 in, result out
  __shared__ __align__(16) u16 Xs[64*256];   // 32 KB
  __shared__ __align__(16) u16 Ws[64*256];   // 32 KB: W1' [64][256] or W2' [256][64]
  __shared__ __align__(16) u16 Hs[64*64];    // 8 KB
  const int t = threadIdx.x, wave = t >> 6, lane = t & 63;
  const int g = lane >> 4, c0 = lane & 15;
  const int row0 = blockIdx.x * 64;

  // stage Xs: [64][256] (8 loads/thread)
#pragma unroll
  for (int p = 0; p < 8; ++p) {
    int i = p*256 + t, r = i >> 5, cb = i & 31;
    __builtin_amdgcn_global_load_lds(
      (const __attribute__((address_space(1))) void*)(A + (size_t)(row0 + r)*CDIM + ((cb ^ (r & 7))*8)),
      (__attribute__((address_space(3))) void*)(Xs + i*8), 16, 0, 0);
  }
  f32x4 acc2[4][4];
#pragma unroll
  for (int m = 0; m < 4; ++m)
#pragma unroll
    for (int n = 0; n < 4; ++n) acc2[m][n] = (f32x4){0.f,0.f,0.f,0.f};

#pragma unroll 1
  for (int hc2 = 0; hc2 < 16; ++hc2) {
    // ---- stage W1' [64 hidden][256 k] (8 loads); Ws free per loop-end barrier ----
#pragma unroll
    for (int p = 0; p < 8; ++p) {
      int i = p*256 + t, r = i >> 5, cb = i & 31;
      __builtin_amdgcn_global_load_lds(
        (const __attribute__((address_space(1))) void*)(W1T + (size_t)(hc2*64 + r)*256 + ((cb ^ (r & 7))*8)),
        (__attribute__((address_space(3))) void*)(Ws + i*8), 16, 0, 0);
    }
    asm volatile("s_waitcnt vmcnt(0)" ::: "memory");
    __syncthreads();                       // W1' (+Xs first iter) ready
    // ---- FC1: 32 MFMAs, uninterrupted ----
    f32x4 acc1[4];
#pragma unroll
    for (int m = 0; m < 4; ++m) acc1[m] = (f32x4){0.f,0.f,0.f,0.f};
#pragma unroll
    for (int q = 0; q < 8; ++q) {          // k-chunk 0..7 over K=256
      s16x8 af[4];
#pragma unroll
      for (int m = 0; m < 4; ++m) {
        int r = m*16 + c0;
        af[m] = *(const s16x8*)&Xs[r*256 + (((q*4 + g) ^ (r & 7))*8)];
      }
      int rw = wave*16 + c0;
      s16x8 bf = *(const s16x8*)&Ws[rw*256 + (((q*4 + g) ^ (rw & 7))*8)];
#pragma unroll
      for (int m = 0; m < 4; ++m)
        acc1[m] = __builtin_amdgcn_mfma_f32_16x16x32_bf16(bf, af[m], acc1[m], 0, 0, 0);
    }
    __syncthreads();                       // all W1' reads done; Ws free
    // ---- issue W2' [256 out][64 k] (8 loads), hidden under GELU ----
#pragma unroll
    for (int p = 0; p < 8; ++p) {
      int i = p*256 + t, r = i >> 3, cb = i & 7;
      __builtin_amdgcn_global_load_lds(
        (const __attribute__((address_space(1))) void*)(W2T + (size_t)r*NHID + hc2*64 + ((cb ^ (r & 7))*8)),
        (__attribute__((address_space(3))) void*)(Ws + i*8), 16, 0, 0);
    }
    // ---- GELU -> Hs [64][64] swizzled (result col = wave*16 + g*4 + j) ----
    {
      const float4 bv = *(const float4*)(b1 + hc2*64 + wave*16 + g*4);
#pragma unroll
      for (int m = 0; m < 4; ++m) {
        int r = m*16 + c0;
        ushort4 o;
        o.x = f2bf(gelu_fast(acc1[m][0] + bv.x));
        o.y = f2bf(gelu_fast(acc1[m][1] + bv.y));
        o.z = f2bf(gelu_fast(acc1[m][2] + bv.z));
        o.w = f2bf(gelu_fast(acc1[m][3] + bv.w));
        int colb = wave*2 + (g >> 1);      // 16B chunk 0..7
        *(ushort4*)((char*)Hs + r*128 + ((colb ^ (r & 7)) << 4) + (g & 1)*8) = o;
      }
    }
    asm volatile("s_waitcnt vmcnt(0)" ::: "memory");
    __syncthreads();                       // W2' + Hs ready
    // ---- FC2: 32 MFMAs, uninterrupted (accumulate into acc2) ----
#pragma unroll
    for (int kk = 0; kk < 2; ++kk) {
      s16x8 af[4], bf[4];
#pragma unroll
      for (int m = 0; m < 4; ++m) {
        int r = m*16 + c0;
        af[m] = *(const s16x8*)&Hs[r*64 + (((kk*4 + g) ^ (r & 7))*8)];
      }
#pragma unroll
      for (int n = 0; n < 4; ++n) {
        int rw = wave*64 + n*16 + c0;
        bf[n] = *(const s16x8*)&Ws[rw*64 + (((kk*4 + g) ^ (rw & 7))*8)];
      }
#pragma unroll
      for (int m = 0; m < 4; ++m)
#pragma unroll
        for (int n = 0; n < 4; ++n)
          acc2[m][n] = __builtin_amdgcn_mfma_f32_16x16x32_bf16(bf[n], af[m], acc2[m][n], 0, 0, 0);
    }
    __syncthreads();                       // Ws + Hs reads done before next hc2
  }
  // ---- epilogue: out = x1 + acc2 + b2
  float4 b2v[4];
#pragma unroll
  for (int n = 0; n < 4; ++n) b2v[n] = *(const float4*)(b2 + wave*64 + n*16 + g*4);
#pragma unroll
  for (int m = 0; m < 4; ++m) {
    size_t base = (size_t)(row0 + m*16 + c0)*CDIM + wave*64 + g*4;
#pragma unroll
    for (int n = 0; n < 4; ++n) {
      float4 rv = *(const float4*)(out + base + n*16);
      float4 o;
      o.x = rv.x + acc2[m][n][0] + b2v[n].x;
      o.y = rv.y + acc2[m][n][1] + b2v[n].y;
      o.z = rv.z + acc2[m][n][2] + b2v[n].z;
      o.w = rv.w + acc2[m][n][3] + b2v[n].w;
      *(float4*)(out + base + n*16) = o;
    }
  }
}

// ---------------- windowed attention ----------------
__global__ __launch_bounds__(256) void attn_kernel(const u16* __restrict__ qkv,
                                                   const float* __restrict__ rpb,
                                                   u16* __restrict__ out) {
  __shared__ __align__(16) u16 VT[NHEADS*HDIM*NWIN];
  __shared__ __align__(16) u16 Pl[4*NWIN*NWIN];
  __shared__ float biasl[NHEADS][128];
  const int t = threadIdx.x, wave = t >> 6, lane = t & 63;
  const int g = lane >> 4, c0 = lane & 15;
  const size_t rowbase = (size_t)blockIdx.x * NWIN;

  for (int e = t; e < NHEADS*128; e += 256) {
    int h = e >> 7, i = e & 127;
    biasl[h][i] = (i < 2*NWIN-1) ? rpb[i*NHEADS + h] : 0.f;
  }
  {
    int cA = t >> 5;
    int inner = t & 31;
    int hh = inner >> 2, d0 = (inner & 3) * 8;
#pragma unroll
    for (int p = 0; p < 8; ++p) {
      int c = p*8 + cA;
      s16x8 v = *(const s16x8*)&qkv[(rowbase + c)*768 + 512 + hh*32 + d0];
#pragma unroll
      for (int j = 0; j < 8; ++j) {
        int d = d0 + j;
        int slot = (c >> 3) ^ (d & 7) ^ hh;
        *(u16*)((char*)VT + hh*4096 + d*128 + slot*16 + (c & 7)*2) = (u16)v[j];
      }
    }
  }
  __syncthreads();

  const float scale = 0.17677669529663687f;
#pragma unroll 1
  for (int rep = 0; rep < 2; ++rep) {
    const int h = wave*2 + rep;
    s16x8 qf[4], kf[4];
#pragma unroll
    for (int m = 0; m < 4; ++m)
      qf[m] = *(const s16x8*)&qkv[(rowbase + m*16 + c0)*768 + h*32 + g*8];
#pragma unroll
    for (int n = 0; n < 4; ++n)
      kf[n] = *(const s16x8*)&qkv[(rowbase + n*16 + c0)*768 + 256 + h*32 + g*8];
    f32x4 sa[4][4];
#pragma unroll
    for (int m = 0; m < 4; ++m)
#pragma unroll
      for (int n = 0; n < 4; ++n) sa[m][n] = (f32x4){0.f,0.f,0.f,0.f};
#pragma unroll
    for (int m = 0; m < 4; ++m)
#pragma unroll
      for (int n = 0; n < 4; ++n)
        sa[m][n] = __builtin_amdgcn_mfma_f32_16x16x32_bf16(qf[m], kf[n], sa[m][n], 0, 0, 0);
#pragma unroll
    for (int m = 0; m < 4; ++m)
#pragma unroll
      for (int n = 0; n < 4; ++n) {
        int idx0 = (m-n)*16 + 4*g - c0 + 63;
#pragma unroll
        for (int j = 0; j < 4; ++j)
          sa[m][n][j] = sa[m][n][j]*scale + biasl[h][idx0 + j];
      }
    float rm[4][4], rsum[4][4];
#pragma unroll
    for (int m = 0; m < 4; ++m)
#pragma unroll
      for (int j = 0; j < 4; ++j) {
        float mx = fmaxf(fmaxf(sa[m][0][j], sa[m][1][j]), fmaxf(sa[m][2][j], sa[m][3][j]));
        mx = fmaxf(mx, __shfl_xor(mx, 1));
        mx = fmaxf(mx, __shfl_xor(mx, 2));
        mx = fmaxf(mx, __shfl_xor(mx, 4));
        mx = fmaxf(mx, __shfl_xor(mx, 8));
        rm[m][j] = mx;
      }
#pragma unroll
    for (int m = 0; m < 4; ++m)
#pragma unroll
      for (int n = 0; n < 4; ++n)
#pragma unroll
        for (int j = 0; j < 4; ++j)
          sa[m][n][j] = __expf(sa[m][n][j] - rm[m][j]);
#pragma unroll
    for (int m = 0; m < 4; ++m)
#pragma unroll
      for (int j = 0; j < 4; ++j) {
        float s = sa[m][0][j] + sa[m][1][j] + sa[m][2][j] + sa[m][3][j];
        s += __shfl_xor(s, 1);
        s += __shfl_xor(s, 2);
        s += __shfl_xor(s, 4);
        s += __shfl_xor(s, 8);
        rsum[m][j] = 1.f / s;
      }
    asm volatile("s_waitcnt lgkmcnt(0)" ::: "memory");
#pragma unroll
    for (int m = 0; m < 4; ++m)
#pragma unroll
      for (int n = 0; n < 4; ++n)
#pragma unroll
        for (int j = 0; j < 4; ++j) {
          int r = m*16 + 4*g + j, c = n*16 + c0;
          *(u16*)((char*)Pl + wave*8192 + r*128 + (((c>>3)^(r&7))*16) + (c&7)*2)
            = f2bf(sa[m][n][j] * rsum[m][j]);
        }
    asm volatile("s_waitcnt lgkmcnt(0)" ::: "memory");
    __builtin_amdgcn_sched_barrier(0);
    f32x4 oa[4][2];
#pragma unroll
    for (int m = 0; m < 4; ++m) { oa[m][0] = (f32x4){0.f,0.f,0.f,0.f}; oa[m][1] = (f32x4){0.f,0.f,0.f,0.f}; }
#pragma unroll
    for (int kk = 0; kk < 2; ++kk) {
      s16x8 pa[4], vb[2];
#pragma unroll
      for (int m = 0; m < 4; ++m) {
        int r = m*16 + c0;
        int slot = (kk*4 + g) ^ (r & 7);
        pa[m] = *(const s16x8*)((const char*)Pl + wave*8192 + r*128 + slot*16);
      }
#pragma unroll
      for (int n = 0; n < 2; ++n) {
        int d = n*16 + c0;
        int slot = (kk*4 + g) ^ (d & 7) ^ h;
        vb[n] = *(const s16x8*)((const char*)VT + h*4096 + d*128 + slot*16);
      }
#pragma unroll
      for (int m = 0; m < 4; ++m)
#pragma unroll
        for (int n = 0; n < 2; ++n)
          oa[m][n] = __builtin_amdgcn_mfma_f32_16x16x32_bf16(vb[n], pa[m], oa[m][n], 0, 0, 0);
    }
#pragma unroll
    for (int m = 0; m < 4; ++m) {
      u16* op = out + (rowbase + m*16 + c0)*CDIM + h*32 + g*4;
#pragma unroll
      for (int n = 0; n < 2; ++n) {
        ushort4 o;
        o.x = f2bf(oa[m][n][0]); o.y = f2bf(oa[m][n][1]);
        o.z = f2bf(oa[m][n][2]); o.w = f2bf(oa[m][n][3]);
        *(ushort4*)(op + n*16) = o;
      }
    }
  }
}

extern "C" void kernel_launch(void* const* d_in, const int* in_sizes, int n_in,
                              void* d_out, int out_size, void* d_ws, size_t ws_size,
                              hipStream_t stream) {
  const float* x      = (const float*)d_in[0];
  const float* g1     = (const float*)d_in[1];
  const float* b1     = (const float*)d_in[2];
  const float* qkv_w  = (const float*)d_in[3];
  const float* qkv_b  = (const float*)d_in[4];
  const float* rpb    = (const float*)d_in[5];
  const float* proj_w = (const float*)d_in[6];
  const float* proj_b = (const float*)d_in[7];
  const float* g2     = (const float*)d_in[8];
  const float* b2     = (const float*)d_in[9];
  const float* fc1_w  = (const float*)d_in[10];
  const float* fc1_b  = (const float*)d_in[11];
  const float* fc2_w  = (const float*)d_in[12];
  const float* fc2_b  = (const float*)d_in[13];
  float* out = (float*)d_out;

  u16* R0     = (u16*)d_ws;
  u16* R1     = R0 + (size_t)MROWS*768;
  u16* qkvwT  = R1 + (size_t)MROWS*1024;
  u16* projwT = qkvwT + 768*256;
  u16* fc1wT  = projwT + 256*256;
  u16* fc2wT  = fc1wT + 1024*256;

  wtrans_kernel<<<dim3(4, 12), 256, 0, stream>>>(qkv_w, qkvwT, 256, 768);
  wtrans_kernel<<<dim3(4, 4),  256, 0, stream>>>(proj_w, projwT, 256, 256);
  wtrans_kernel<<<dim3(4, 16), 256, 0, stream>>>(fc1_w, fc1wT, 256, 1024);
  wtrans_kernel<<<dim3(16, 4), 256, 0, stream>>>(fc2_w, fc2wT, 1024, 256);

  constexpr int NT_M = MROWS/128;
  ln_shift_kernel<<<MROWS/4, 256, 0, stream>>>(x, g1, b1, R1);
  gemm_kernel<256, 768><<<NT_M*6, 256, 0, stream>>>(R1, qkvwT, qkv_b, R0);
  attn_kernel<<<MROWS/NWIN, 256, 0, stream>>>(R0, rpb, R1);
  proj_ln_kernel<<<MROWS/64, 256, 0, stream>>>(R1, projwT, proj_b, x, g2, b2, out, R0);
  mlp_kernel<<<MROWS/64, 256, 0, stream>>>(R0, fc1wT, fc2wT, fc1_b, fc2_b, out);
}